// Round 1
// baseline (428.551 us; speedup 1.0000x reference)
//
#include <hip/hip_runtime.h>
#include <hip/hip_bf16.h>

// Problem: lstm_20169166422798
// x:(64,512,513) W_ih:(200,513) W_hh:(200,50) b_ih:(200) b_hh:(200)
// W_out:(513,50) b_out:(513)  -> out:(64,512,513) fp32
//
// Pipeline:
//  K1: xg[m][g] = x[m][:] . W_ih[g][:] + b_ih[g]      (m = b*512+t, fp32 tiled GEMM)
//  K2: recurrence over b (64 steps), 512 independent t-rows, H=50 state
//  K3: out[m][f] = hs[m][:] . W_out[f][:] + b_out[f]  (K=50 GEMM)

#define B_SZ 64
#define T_SZ 512
#define F_SZ 513
#define H_SZ 50
#define G_SZ 200            // 4*H
#define M_SZ (B_SZ * T_SZ)  // 32768

// ---------------------------------------------------------------- K1: xg GEMM
// C(32768 x 200) = X(32768 x 513) * W_ih^T + b_ih
// 128x128 tiles (2 col tiles cover N=200), BK=16, 256 thr, 8x8 reg tile.
__global__ __launch_bounds__(256) void gemm_xg(
    const float* __restrict__ x, const float* __restrict__ Wih,
    const float* __restrict__ bih, float* __restrict__ xg) {
  const int K = F_SZ;
  int n0 = blockIdx.x * 128;  // 0 or 128
  int m0 = blockIdx.y * 128;
  __shared__ __align__(16) float As[16][128];  // [kk][m]
  __shared__ __align__(16) float Bs[16][128];  // [kk][n]
  int tid = threadIdx.x;
  int tm = tid >> 4, tn = tid & 15;
  int lr = tid >> 1;  // staging row 0..127
  int lq = tid & 1;   // staging k-half

  float acc[8][8];
#pragma unroll
  for (int r = 0; r < 8; r++)
#pragma unroll
    for (int c = 0; c < 8; c++) acc[r][c] = 0.f;

  for (int k0 = 0; k0 < K; k0 += 16) {
#pragma unroll
    for (int i = 0; i < 8; i++) {
      int kk = lq * 8 + i;
      int k = k0 + kk;
      float va = (k < K) ? x[(size_t)(m0 + lr) * K + k] : 0.f;
      As[kk][lr] = va;
      int n = n0 + lr;
      float vb = (k < K && n < G_SZ) ? Wih[(size_t)n * K + k] : 0.f;
      Bs[kk][lr] = vb;
    }
    __syncthreads();
#pragma unroll
    for (int kk = 0; kk < 16; kk++) {
      float4 a0 = *(const float4*)&As[kk][tm * 8];
      float4 a1 = *(const float4*)&As[kk][tm * 8 + 4];
      float4 b0 = *(const float4*)&Bs[kk][tn * 8];
      float4 b1 = *(const float4*)&Bs[kk][tn * 8 + 4];
      float a[8] = {a0.x, a0.y, a0.z, a0.w, a1.x, a1.y, a1.z, a1.w};
      float b[8] = {b0.x, b0.y, b0.z, b0.w, b1.x, b1.y, b1.z, b1.w};
#pragma unroll
      for (int r = 0; r < 8; r++)
#pragma unroll
        for (int c = 0; c < 8; c++) acc[r][c] = fmaf(a[r], b[c], acc[r][c]);
    }
    __syncthreads();
  }

  int cn = n0 + tn * 8;
  if (cn < G_SZ) {  // N=200 is a multiple of 8, so full float4x2 chunks
    float4 bi0 = *(const float4*)&bih[cn];
    float4 bi1 = *(const float4*)&bih[cn + 4];
#pragma unroll
    for (int r = 0; r < 8; r++) {
      size_t m = (size_t)(m0 + tm * 8 + r);
      float4 o0 = make_float4(acc[r][0] + bi0.x, acc[r][1] + bi0.y,
                              acc[r][2] + bi0.z, acc[r][3] + bi0.w);
      float4 o1 = make_float4(acc[r][4] + bi1.x, acc[r][5] + bi1.y,
                              acc[r][6] + bi1.z, acc[r][7] + bi1.w);
      *(float4*)&xg[m * G_SZ + cn] = o0;
      *(float4*)&xg[m * G_SZ + cn + 4] = o1;
    }
  }
}

// ------------------------------------------------------------- K2: recurrence
__device__ __forceinline__ float sig_f(float v) {
  return 1.0f / (1.0f + __expf(-v));
}
__device__ __forceinline__ float tanh_f(float v) {
  return 2.0f / (1.0f + __expf(-2.0f * v)) - 1.0f;
}

// One block (128 thr) per t. Threads 0..99 each own 2 gate rows of W_hh in
// registers; h broadcast through LDS; c lives in thread j (<50) registers.
__global__ __launch_bounds__(128) void lstm_rec(
    const float* __restrict__ xg, const float* __restrict__ Whh,
    const float* __restrict__ bhh, float* __restrict__ hs) {
  int t = blockIdx.x;
  int tid = threadIdx.x;
  __shared__ __align__(16) float h_s[52];
  __shared__ __align__(16) float gact[200];

  float w0[50], w1[50];
  float bh0 = 0.f, bh1 = 0.f;
  bool gatet = (tid < 100);
  bool is_tanh = (tid >= 50 && tid < 75);  // gates 100..149 = g-gate
  if (gatet) {
    int g0 = 2 * tid;
#pragma unroll
    for (int j = 0; j < 50; j++) {
      w0[j] = Whh[(size_t)g0 * H_SZ + j];
      w1[j] = Whh[(size_t)(g0 + 1) * H_SZ + j];
    }
    bh0 = bhh[g0];
    bh1 = bhh[g0 + 1];
  }
  if (tid < 52) h_s[tid] = 0.f;
  __syncthreads();

  const float* xgt = xg + (size_t)t * G_SZ;
  const size_t bstride = (size_t)T_SZ * G_SZ;  // 102400
  float c = 0.f;

  float2 xnext = make_float2(0.f, 0.f);
  if (gatet) xnext = *(const float2*)(xgt + 2 * tid);

  for (int b = 0; b < B_SZ; b++) {
    float2 xcur = xnext;
    if (gatet && b < B_SZ - 1)
      xnext = *(const float2*)(xgt + (size_t)(b + 1) * bstride + 2 * tid);

    if (gatet) {
      float acc0 = xcur.x + bh0;
      float acc1 = xcur.y + bh1;
      const float4* h4 = (const float4*)h_s;
#pragma unroll
      for (int jq = 0; jq < 12; jq++) {
        float4 hv = h4[jq];
        acc0 = fmaf(hv.x, w0[4 * jq + 0], acc0);
        acc0 = fmaf(hv.y, w0[4 * jq + 1], acc0);
        acc0 = fmaf(hv.z, w0[4 * jq + 2], acc0);
        acc0 = fmaf(hv.w, w0[4 * jq + 3], acc0);
        acc1 = fmaf(hv.x, w1[4 * jq + 0], acc1);
        acc1 = fmaf(hv.y, w1[4 * jq + 1], acc1);
        acc1 = fmaf(hv.z, w1[4 * jq + 2], acc1);
        acc1 = fmaf(hv.w, w1[4 * jq + 3], acc1);
      }
      float2 ht = *(const float2*)&h_s[48];
      acc0 = fmaf(ht.x, w0[48], acc0);
      acc0 = fmaf(ht.y, w0[49], acc0);
      acc1 = fmaf(ht.x, w1[48], acc1);
      acc1 = fmaf(ht.y, w1[49], acc1);
      float a0 = is_tanh ? tanh_f(acc0) : sig_f(acc0);
      float a1 = is_tanh ? tanh_f(acc1) : sig_f(acc1);
      *(float2*)&gact[2 * tid] = make_float2(a0, a1);
    }
    __syncthreads();
    if (tid < H_SZ) {
      float iv = gact[tid];
      float fv = gact[50 + tid];
      float gv = gact[100 + tid];
      float ov = gact[150 + tid];
      c = fmaf(fv, c, iv * gv);
      float hv = ov * tanh_f(c);
      h_s[tid] = hv;
      hs[(size_t)b * (T_SZ * H_SZ) + (size_t)t * H_SZ + tid] = hv;
    }
    __syncthreads();
  }
}

// ---------------------------------------------------------------- K3: out GEMM
// out(32768 x 513) = hs(32768 x 50) * W_out^T + b_out. 128x64 tiles, full K.
__global__ __launch_bounds__(256) void gemm_out(
    const float* __restrict__ hs, const float* __restrict__ Wout,
    const float* __restrict__ bout, float* __restrict__ out) {
  int n0 = blockIdx.x * 64;
  int m0 = blockIdx.y * 128;
  __shared__ float As[128][53];  // [m][kk], pad 53 -> conflict-free frag reads
  __shared__ float Bs[50][64];   // [kk][n]
  int tid = threadIdx.x;
  int tm = tid >> 4, tn = tid & 15;

#pragma unroll
  for (int i = 0; i < 25; i++) {  // 128*50 = 6400 elems, coalesced
    int e = tid + 256 * i;
    As[e / 50][e % 50] = hs[(size_t)m0 * H_SZ + e];
  }
#pragma unroll
  for (int i = 0; i < 13; i++) {  // 50*64 = 3200 elems
    int e = tid + 256 * i;
    if (e < 3200) {
      int kk = e >> 6, cc = e & 63;
      int n = n0 + cc;
      Bs[kk][cc] = (n < F_SZ) ? Wout[(size_t)n * H_SZ + kk] : 0.f;
    }
  }
  __syncthreads();

  float acc[8][4];
#pragma unroll
  for (int r = 0; r < 8; r++)
#pragma unroll
    for (int c = 0; c < 4; c++) acc[r][c] = 0.f;

#pragma unroll 5
  for (int kk = 0; kk < 50; kk++) {
    float a[8], b[4];
#pragma unroll
    for (int r = 0; r < 8; r++) a[r] = As[tm * 8 + r][kk];
#pragma unroll
    for (int c = 0; c < 4; c++) b[c] = Bs[kk][tn + 16 * c];
#pragma unroll
    for (int r = 0; r < 8; r++)
#pragma unroll
      for (int c = 0; c < 4; c++) acc[r][c] = fmaf(a[r], b[c], acc[r][c]);
  }

#pragma unroll
  for (int r = 0; r < 8; r++) {
    size_t m = (size_t)(m0 + tm * 8 + r);
#pragma unroll
    for (int c = 0; c < 4; c++) {
      int n = n0 + tn + 16 * c;  // strided cols -> coalesced scalar stores
      if (n < F_SZ) out[m * F_SZ + n] = acc[r][c] + bout[n];
    }
  }
}

extern "C" void kernel_launch(void* const* d_in, const int* in_sizes, int n_in,
                              void* d_out, int out_size, void* d_ws,
                              size_t ws_size, hipStream_t stream) {
  const float* x = (const float*)d_in[0];
  const float* Wih = (const float*)d_in[1];
  const float* Whh = (const float*)d_in[2];
  const float* bih = (const float*)d_in[3];
  const float* bhh = (const float*)d_in[4];
  const float* Wout = (const float*)d_in[5];
  const float* bout = (const float*)d_in[6];
  float* out = (float*)d_out;

  float* xg = (float*)d_ws;                    // 32768*200 floats = 26.2 MB
  float* hs = xg + (size_t)M_SZ * G_SZ;        // 32768*50 floats  = 6.6 MB

  dim3 gA(2, M_SZ / 128, 1);
  gemm_xg<<<gA, 256, 0, stream>>>(x, Wih, bih, xg);

  lstm_rec<<<T_SZ, 128, 0, stream>>>(xg, Whh, bhh, hs);

  dim3 gC((F_SZ + 63) / 64, M_SZ / 128, 1);
  gemm_out<<<gC, 256, 0, stream>>>(hs, Wout, bout, out);
}

// Round 2
// 335.925 us; speedup vs baseline: 1.2757x; 1.2757x over previous
//
#include <hip/hip_runtime.h>
#include <hip/hip_bf16.h>

// Problem: lstm_20169166422798
// x:(64,512,513) W_ih:(200,513) W_hh:(200,50) b_ih:(200) b_hh:(200)
// W_out:(513,50) b_out:(513)  -> out:(64,512,513) fp32

#define B_SZ 64
#define T_SZ 512
#define F_SZ 513
#define H_SZ 50
#define G_SZ 200            // 4*H
#define M_SZ (B_SZ * T_SZ)  // 32768

// ---------------------------------------------------------------- K1: xg GEMM
// C(32768 x 200) = X(32768 x 513) * W_ih^T + b_ih
// BM=32, BN=200 (full N, no column waste), BK=32, 256 thr.
// Thread grid 8(m-groups of 4) x 25(n-groups of 8); threads 200..255 stage only.
// Register-prefetch software pipeline; As[kk][m] pad36 / Bs[kk][n] pad212 give
// conflict-free ds_read_b128 fragment reads (a: 8 distinct tm -> 32 banks once;
// b: tn*8 -> 4-way worst on 2 instrs/kk, cheap per m136).
__global__ __launch_bounds__(256) void gemm_xg(
    const float* __restrict__ x, const float* __restrict__ Wih,
    const float* __restrict__ bih, float* __restrict__ xg) {
  const int K = F_SZ;
  int m0 = blockIdx.x * 32;
  __shared__ __align__(16) float As[32][36];
  __shared__ __align__(16) float Bs[32][212];
  int tid = threadIdx.x;
  int kk = tid & 31;   // staging k within slab (lane-contiguous -> coalesced)
  int r0 = tid >> 5;   // staging row base (0..7)
  bool compute = (tid < 200);
  int tm = tid / 25;   // 0..7  (4 m-rows each)
  int tn = tid % 25;   // 0..24 (8 n-cols each)

  float acc[4][8];
#pragma unroll
  for (int r = 0; r < 4; r++)
#pragma unroll
    for (int c = 0; c < 8; c++) acc[r][c] = 0.f;

  float pa[4], pb[25];

  // ---- prefetch tile 0
  {
    int k = kk;  // k0 = 0, always < 513
#pragma unroll
    for (int i = 0; i < 4; i++)
      pa[i] = x[(size_t)(m0 + r0 + 8 * i) * K + k];
#pragma unroll
    for (int i = 0; i < 25; i++)
      pb[i] = Wih[(size_t)(r0 + 8 * i) * K + k];
  }
  // store tile 0 to LDS
#pragma unroll
  for (int i = 0; i < 4; i++) As[kk][r0 + 8 * i] = pa[i];
#pragma unroll
  for (int i = 0; i < 25; i++) Bs[kk][r0 + 8 * i] = pb[i];
  __syncthreads();

  const int NT = 17;  // ceil(513/32)
  for (int t = 0; t < NT; t++) {
    // prefetch tile t+1 into registers (overlaps with compute below)
    if (t < NT - 1) {
      int k0 = (t + 1) * 32;
      int k = k0 + kk;
      bool ok = (k < K);  // only last slab (k0=512) is partial
#pragma unroll
      for (int i = 0; i < 4; i++)
        pa[i] = ok ? x[(size_t)(m0 + r0 + 8 * i) * K + k] : 0.f;
#pragma unroll
      for (int i = 0; i < 25; i++)
        pb[i] = ok ? Wih[(size_t)(r0 + 8 * i) * K + k] : 0.f;
    }

    if (compute) {
#pragma unroll 8
      for (int q = 0; q < 32; q++) {
        float4 av = *(const float4*)&As[q][tm * 4];
        float4 b0 = *(const float4*)&Bs[q][tn * 8];
        float4 b1 = *(const float4*)&Bs[q][tn * 8 + 4];
        float a[4] = {av.x, av.y, av.z, av.w};
        float b[8] = {b0.x, b0.y, b0.z, b0.w, b1.x, b1.y, b1.z, b1.w};
#pragma unroll
        for (int r = 0; r < 4; r++)
#pragma unroll
          for (int c = 0; c < 8; c++) acc[r][c] = fmaf(a[r], b[c], acc[r][c]);
      }
    }
    __syncthreads();
    if (t < NT - 1) {
#pragma unroll
      for (int i = 0; i < 4; i++) As[kk][r0 + 8 * i] = pa[i];
#pragma unroll
      for (int i = 0; i < 25; i++) Bs[kk][r0 + 8 * i] = pb[i];
      __syncthreads();
    }
  }

  if (compute) {
    float4 bi0 = *(const float4*)&bih[tn * 8];
    float4 bi1 = *(const float4*)&bih[tn * 8 + 4];
#pragma unroll
    for (int r = 0; r < 4; r++) {
      size_t m = (size_t)(m0 + tm * 4 + r);
      float4 o0 = make_float4(acc[r][0] + bi0.x, acc[r][1] + bi0.y,
                              acc[r][2] + bi0.z, acc[r][3] + bi0.w);
      float4 o1 = make_float4(acc[r][4] + bi1.x, acc[r][5] + bi1.y,
                              acc[r][6] + bi1.z, acc[r][7] + bi1.w);
      *(float4*)&xg[m * G_SZ + tn * 8] = o0;
      *(float4*)&xg[m * G_SZ + tn * 8 + 4] = o1;
    }
  }
}

// ------------------------------------------------------------- K2: recurrence
__device__ __forceinline__ float sig_f(float v) {
  return 1.0f / (1.0f + __expf(-v));
}
__device__ __forceinline__ float tanh_f(float v) {
  return 2.0f / (1.0f + __expf(-2.0f * v)) - 1.0f;
}

__global__ __launch_bounds__(128) void lstm_rec(
    const float* __restrict__ xg, const float* __restrict__ Whh,
    const float* __restrict__ bhh, float* __restrict__ hs) {
  int t = blockIdx.x;
  int tid = threadIdx.x;
  __shared__ __align__(16) float h_s[52];
  __shared__ __align__(16) float gact[200];

  float w0[50], w1[50];
  float bh0 = 0.f, bh1 = 0.f;
  bool gatet = (tid < 100);
  bool is_tanh = (tid >= 50 && tid < 75);  // gates 100..149 = g-gate
  if (gatet) {
    int g0 = 2 * tid;
#pragma unroll
    for (int j = 0; j < 50; j++) {
      w0[j] = Whh[(size_t)g0 * H_SZ + j];
      w1[j] = Whh[(size_t)(g0 + 1) * H_SZ + j];
    }
    bh0 = bhh[g0];
    bh1 = bhh[g0 + 1];
  }
  if (tid < 52) h_s[tid] = 0.f;
  __syncthreads();

  const float* xgt = xg + (size_t)t * G_SZ;
  const size_t bstride = (size_t)T_SZ * G_SZ;  // 102400
  float c = 0.f;

  float2 xnext = make_float2(0.f, 0.f);
  if (gatet) xnext = *(const float2*)(xgt + 2 * tid);

  for (int b = 0; b < B_SZ; b++) {
    float2 xcur = xnext;
    if (gatet && b < B_SZ - 1)
      xnext = *(const float2*)(xgt + (size_t)(b + 1) * bstride + 2 * tid);

    if (gatet) {
      float acc0 = xcur.x + bh0;
      float acc1 = xcur.y + bh1;
      const float4* h4 = (const float4*)h_s;
#pragma unroll
      for (int jq = 0; jq < 12; jq++) {
        float4 hv = h4[jq];
        acc0 = fmaf(hv.x, w0[4 * jq + 0], acc0);
        acc0 = fmaf(hv.y, w0[4 * jq + 1], acc0);
        acc0 = fmaf(hv.z, w0[4 * jq + 2], acc0);
        acc0 = fmaf(hv.w, w0[4 * jq + 3], acc0);
        acc1 = fmaf(hv.x, w1[4 * jq + 0], acc1);
        acc1 = fmaf(hv.y, w1[4 * jq + 1], acc1);
        acc1 = fmaf(hv.z, w1[4 * jq + 2], acc1);
        acc1 = fmaf(hv.w, w1[4 * jq + 3], acc1);
      }
      float2 ht = *(const float2*)&h_s[48];
      acc0 = fmaf(ht.x, w0[48], acc0);
      acc0 = fmaf(ht.y, w0[49], acc0);
      acc1 = fmaf(ht.x, w1[48], acc1);
      acc1 = fmaf(ht.y, w1[49], acc1);
      float a0 = is_tanh ? tanh_f(acc0) : sig_f(acc0);
      float a1 = is_tanh ? tanh_f(acc1) : sig_f(acc1);
      *(float2*)&gact[2 * tid] = make_float2(a0, a1);
    }
    __syncthreads();
    if (tid < H_SZ) {
      float iv = gact[tid];
      float fv = gact[50 + tid];
      float gv = gact[100 + tid];
      float ov = gact[150 + tid];
      c = fmaf(fv, c, iv * gv);
      float hv = ov * tanh_f(c);
      h_s[tid] = hv;
      hs[(size_t)b * (T_SZ * H_SZ) + (size_t)t * H_SZ + tid] = hv;
    }
    __syncthreads();
  }
}

// ---------------------------------------------------------------- K3: out GEMM
// out(32768 x 513) = hs(32768 x 50) * W_out^T + b_out. 128x64 tiles, full K.
__global__ __launch_bounds__(256) void gemm_out(
    const float* __restrict__ hs, const float* __restrict__ Wout,
    const float* __restrict__ bout, float* __restrict__ out) {
  int n0 = blockIdx.x * 64;
  int m0 = blockIdx.y * 128;
  __shared__ float As[128][53];
  __shared__ float Bs[50][64];
  int tid = threadIdx.x;
  int tm = tid >> 4, tn = tid & 15;

#pragma unroll
  for (int i = 0; i < 25; i++) {  // 128*50 = 6400 elems, coalesced
    int e = tid + 256 * i;
    As[e / 50][e % 50] = hs[(size_t)m0 * H_SZ + e];
  }
#pragma unroll
  for (int i = 0; i < 13; i++) {  // 50*64 = 3200 elems
    int e = tid + 256 * i;
    if (e < 3200) {
      int kk = e >> 6, cc = e & 63;
      int n = n0 + cc;
      Bs[kk][cc] = (n < F_SZ) ? Wout[(size_t)n * H_SZ + kk] : 0.f;
    }
  }
  __syncthreads();

  float acc[8][4];
#pragma unroll
  for (int r = 0; r < 8; r++)
#pragma unroll
    for (int c = 0; c < 4; c++) acc[r][c] = 0.f;

#pragma unroll 5
  for (int kk = 0; kk < 50; kk++) {
    float a[8], b[4];
#pragma unroll
    for (int r = 0; r < 8; r++) a[r] = As[tm * 8 + r][kk];
#pragma unroll
    for (int c = 0; c < 4; c++) b[c] = Bs[kk][tn + 16 * c];
#pragma unroll
    for (int r = 0; r < 8; r++)
#pragma unroll
      for (int c = 0; c < 4; c++) acc[r][c] = fmaf(a[r], b[c], acc[r][c]);
  }

#pragma unroll
  for (int r = 0; r < 8; r++) {
    size_t m = (size_t)(m0 + tm * 8 + r);
#pragma unroll
    for (int c = 0; c < 4; c++) {
      int n = n0 + tn + 16 * c;
      if (n < F_SZ) out[m * F_SZ + n] = acc[r][c] + bout[n];
    }
  }
}

extern "C" void kernel_launch(void* const* d_in, const int* in_sizes, int n_in,
                              void* d_out, int out_size, void* d_ws,
                              size_t ws_size, hipStream_t stream) {
  const float* x = (const float*)d_in[0];
  const float* Wih = (const float*)d_in[1];
  const float* Whh = (const float*)d_in[2];
  const float* bih = (const float*)d_in[3];
  const float* bhh = (const float*)d_in[4];
  const float* Wout = (const float*)d_in[5];
  const float* bout = (const float*)d_in[6];
  float* out = (float*)d_out;

  float* xg = (float*)d_ws;                    // 32768*200 floats = 26.2 MB
  float* hs = xg + (size_t)M_SZ * G_SZ;        // 32768*50 floats  = 6.6 MB

  gemm_xg<<<M_SZ / 32, 256, 0, stream>>>(x, Wih, bih, xg);

  lstm_rec<<<T_SZ, 128, 0, stream>>>(xg, Whh, bhh, hs);

  dim3 gC((F_SZ + 63) / 64, M_SZ / 128, 1);
  gemm_out<<<gC, 256, 0, stream>>>(hs, Wout, bout, out);
}

// Round 3
// 289.828 us; speedup vs baseline: 1.4786x; 1.1591x over previous
//
#include <hip/hip_runtime.h>
#include <hip/hip_bf16.h>

// Problem: lstm_20169166422798
// x:(64,512,513) W_ih:(200,513) W_hh:(200,50) b_ih:(200) b_hh:(200)
// W_out:(513,50) b_out:(513)  -> out:(64,512,513) fp32

#define B_SZ 64
#define T_SZ 512
#define F_SZ 513
#define H_SZ 50
#define G_SZ 200            // 4*H
#define M_SZ (B_SZ * T_SZ)  // 32768
#define KPAD 544            // 17*32 (main loop uses 16 slabs; k=512 is a rank-1 tail)
#define NPAD 208            // 13*16

typedef __attribute__((ext_vector_type(8))) short short8;   // bf16x8 MFMA frag
typedef __attribute__((ext_vector_type(4))) float f32x4;    // MFMA acc

__device__ __forceinline__ float bf2f(unsigned short u) {
  unsigned int v = ((unsigned int)u) << 16;
  return __builtin_bit_cast(float, v);
}
__device__ __forceinline__ unsigned short f2bf(float f) {
  // RNE round to bf16
  unsigned int b = __builtin_bit_cast(unsigned int, f);
  unsigned int r = b + 0x7FFFu + ((b >> 16) & 1u);
  return (unsigned short)(r >> 16);
}

// -------------------------------------------- K0: W_ih -> bf16, zero-padded
__global__ __launch_bounds__(256) void conv_wih(const float* __restrict__ Wih,
                                                unsigned short* __restrict__ Wb) {
  int idx = blockIdx.x * 256 + threadIdx.x;
  if (idx >= NPAD * KPAD) return;
  int n = idx / KPAD, k = idx % KPAD;
  float v = (n < G_SZ && k < F_SZ) ? Wih[(size_t)n * F_SZ + k] : 0.f;
  Wb[idx] = f2bf(v);
}

// ---------------------------------------------------------------- K1: xg GEMM
// xg(32768 x 200, bf16) = X(32768 x 513, fp32) * W_ih^T + b_ih, via bf16 MFMA.
// No LDS, no barriers. Block = 4 independent waves; wave w owns m-tile
// m0+16w..+15 x all 13 n-tiles. A-frag: lane -> row=lane&15, k=(lane>>4)*8+j
// (fp32 load + cvt). B-frag: Wb row n=lane&15 of tile, 8 consecutive k (b128).
// K = 16 full slabs of 32 (k<512, unguarded) + rank-1 VALU tail for k=512.
__global__ __launch_bounds__(256) void gemm_xg_mfma(
    const float* __restrict__ x, const unsigned short* __restrict__ Wb,
    const float* __restrict__ Wih, const float* __restrict__ bih,
    unsigned short* __restrict__ xg) {
  int wave = threadIdx.x >> 6;
  int lane = threadIdx.x & 63;
  int m0 = blockIdx.x * 64 + wave * 16;
  int arow = lane & 15;  // A m-index / B n-index / C col-index
  int kg = lane >> 4;    // k-group

  f32x4 acc[13];
#pragma unroll
  for (int nt = 0; nt < 13; nt++) acc[nt] = (f32x4){0.f, 0.f, 0.f, 0.f};

  const float* xrow = x + (size_t)(m0 + arow) * F_SZ;

#pragma unroll 4
  for (int t = 0; t < 16; t++) {
    int k0 = t * 32 + kg * 8;
    float4 xa = *(const float4*)(xrow + k0);
    float4 xb = *(const float4*)(xrow + k0 + 4);
    short8 af;
    af[0] = (short)f2bf(xa.x); af[1] = (short)f2bf(xa.y);
    af[2] = (short)f2bf(xa.z); af[3] = (short)f2bf(xa.w);
    af[4] = (short)f2bf(xb.x); af[5] = (short)f2bf(xb.y);
    af[6] = (short)f2bf(xb.z); af[7] = (short)f2bf(xb.w);
#pragma unroll
    for (int nt = 0; nt < 13; nt++) {
      short8 bf = *(const short8*)(Wb + (size_t)(nt * 16 + arow) * KPAD + k0);
      acc[nt] = __builtin_amdgcn_mfma_f32_16x16x32_bf16(af, bf, acc[nt], 0, 0, 0);
    }
  }

  // rank-1 tail (k=512) in fp32 + epilogue. C layout: col=lane&15,
  // row=(lane>>4)*4+reg (m89-verified).
  float xv[4];
#pragma unroll
  for (int r = 0; r < 4; r++)
    xv[r] = x[(size_t)(m0 + kg * 4 + r) * F_SZ + 512];

#pragma unroll
  for (int nt = 0; nt < 13; nt++) {
    int n = nt * 16 + arow;
    bool ok = (n < G_SZ);
    float wv = ok ? Wih[(size_t)n * F_SZ + 512] : 0.f;
    float bv = ok ? bih[n] : 0.f;
#pragma unroll
    for (int r = 0; r < 4; r++) {
      float o = fmaf(xv[r], wv, acc[nt][r]) + bv;
      if (ok) xg[(size_t)(m0 + kg * 4 + r) * G_SZ + n] = f2bf(o);
    }
  }
}

// ------------------------------------------------------------- K2: recurrence
__device__ __forceinline__ float sig_f(float v) {
  return 1.0f / (1.0f + __expf(-v));
}
__device__ __forceinline__ float tanh_f(float v) {
  return 2.0f / (1.0f + __expf(-2.0f * v)) - 1.0f;
}

// One wave (64-thread block) per t. Lane j (j<50) owns all 4 gate rows
// {j, 50+j, 100+j, 150+j} of W_hh in 200 VGPRs and the cell state c_j:
// gates, cell update, h_j all in-lane; h broadcast via LDS (write: 2-way free;
// reads: same-address broadcast). Single-wave workgroup -> __syncthreads is a
// near-free ordering fence. 2-step-ahead xg prefetch covers L3 latency.
__global__ __launch_bounds__(64) void lstm_rec(
    const unsigned short* __restrict__ xg, const float* __restrict__ Whh,
    const float* __restrict__ bhh, float* __restrict__ hs) {
  int t = blockIdx.x;
  int j = threadIdx.x;
  int jc = (j < H_SZ) ? j : (H_SZ - 1);  // lanes 50..63 shadow lane 49
  __shared__ __align__(16) float h_s[64];

  float w[4][50];
  float bh[4];
#pragma unroll
  for (int g = 0; g < 4; g++) {
    int grow = jc + 50 * g;
    bh[g] = bhh[grow];
#pragma unroll
    for (int k = 0; k < 50; k++) w[g][k] = Whh[(size_t)grow * H_SZ + k];
  }
  h_s[j] = 0.f;
  float c = 0.f;
  __syncthreads();

  const size_t bstride = (size_t)T_SZ * G_SZ;
  const size_t base = (size_t)t * G_SZ + jc;

  float xf[2][4];
#pragma unroll
  for (int p = 0; p < 2; p++)
#pragma unroll
    for (int g = 0; g < 4; g++)
      xf[p][g] = bf2f(xg[(size_t)p * bstride + base + 50 * g]);

  for (int b = 0; b < B_SZ; b++) {
    int slot = b & 1;
    float a[4];
#pragma unroll
    for (int g = 0; g < 4; g++) a[g] = xf[slot][g] + bh[g];

    if (b + 2 < B_SZ) {
#pragma unroll
      for (int g = 0; g < 4; g++)
        xf[slot][g] = bf2f(xg[(size_t)(b + 2) * bstride + base + 50 * g]);
    }

    const float4* h4 = (const float4*)h_s;
#pragma unroll
    for (int kq = 0; kq < 12; kq++) {
      float4 hv = h4[kq];
#pragma unroll
      for (int g = 0; g < 4; g++) {
        a[g] = fmaf(hv.x, w[g][4 * kq + 0], a[g]);
        a[g] = fmaf(hv.y, w[g][4 * kq + 1], a[g]);
        a[g] = fmaf(hv.z, w[g][4 * kq + 2], a[g]);
        a[g] = fmaf(hv.w, w[g][4 * kq + 3], a[g]);
      }
    }
    float2 hv2 = *(const float2*)(h_s + 48);
#pragma unroll
    for (int g = 0; g < 4; g++) {
      a[g] = fmaf(hv2.x, w[g][48], a[g]);
      a[g] = fmaf(hv2.y, w[g][49], a[g]);
    }

    float iv = sig_f(a[0]);
    float fv = sig_f(a[1]);
    float gv = tanh_f(a[2]);
    float ov = sig_f(a[3]);
    c = fmaf(fv, c, iv * gv);
    float h = ov * tanh_f(c);

    h_s[j] = h;  // lanes 50..63 write junk to h_s[50..63]; never read
    if (j < H_SZ)
      hs[(size_t)b * (T_SZ * H_SZ) + (size_t)t * H_SZ + j] = h;
    __syncthreads();  // write(b) visible before reads(b+1); single-wave: cheap
  }
}

// ---------------------------------------------------------------- K3: out GEMM
// out(32768 x 513) = hs(32768 x 50) * W_out^T + b_out. 128x64 tiles, full K.
__global__ __launch_bounds__(256) void gemm_out(
    const float* __restrict__ hs, const float* __restrict__ Wout,
    const float* __restrict__ bout, float* __restrict__ out) {
  int n0 = blockIdx.x * 64;
  int m0 = blockIdx.y * 128;
  __shared__ float As[128][53];
  __shared__ float Bs[50][64];
  int tid = threadIdx.x;
  int tm = tid >> 4, tn = tid & 15;

#pragma unroll
  for (int i = 0; i < 25; i++) {  // 128*50 = 6400 elems, coalesced
    int e = tid + 256 * i;
    As[e / 50][e % 50] = hs[(size_t)m0 * H_SZ + e];
  }
#pragma unroll
  for (int i = 0; i < 13; i++) {  // 50*64 = 3200 elems
    int e = tid + 256 * i;
    if (e < 3200) {
      int kk = e >> 6, cc = e & 63;
      int n = n0 + cc;
      Bs[kk][cc] = (n < F_SZ) ? Wout[(size_t)n * H_SZ + kk] : 0.f;
    }
  }
  __syncthreads();

  float acc[8][4];
#pragma unroll
  for (int r = 0; r < 8; r++)
#pragma unroll
    for (int c = 0; c < 4; c++) acc[r][c] = 0.f;

#pragma unroll 5
  for (int kk = 0; kk < 50; kk++) {
    float a[8], b[4];
#pragma unroll
    for (int r = 0; r < 8; r++) a[r] = As[tm * 8 + r][kk];
#pragma unroll
    for (int c = 0; c < 4; c++) b[c] = Bs[kk][tn + 16 * c];
#pragma unroll
    for (int r = 0; r < 8; r++)
#pragma unroll
      for (int c = 0; c < 4; c++) acc[r][c] = fmaf(a[r], b[c], acc[r][c]);
  }

#pragma unroll
  for (int r = 0; r < 8; r++) {
    size_t m = (size_t)(m0 + tm * 8 + r);
#pragma unroll
    for (int c = 0; c < 4; c++) {
      int n = n0 + tn + 16 * c;
      if (n < F_SZ) out[m * F_SZ + n] = acc[r][c] + bout[n];
    }
  }
}

extern "C" void kernel_launch(void* const* d_in, const int* in_sizes, int n_in,
                              void* d_out, int out_size, void* d_ws,
                              size_t ws_size, hipStream_t stream) {
  const float* x = (const float*)d_in[0];
  const float* Wih = (const float*)d_in[1];
  const float* Whh = (const float*)d_in[2];
  const float* bih = (const float*)d_in[3];
  const float* bhh = (const float*)d_in[4];
  const float* Wout = (const float*)d_in[5];
  const float* bout = (const float*)d_in[6];
  float* out = (float*)d_out;

  // ws layout (19.9 MB total, < 32.8 MB known-good):
  //   xg_b : bf16 [32768][200]  = 13,107,200 B
  //   hs   : fp32 [64][512][50] =  6,553,600 B
  //   Wb   : bf16 [208][544]    =    226,304 B
  unsigned short* xg_b = (unsigned short*)d_ws;
  float* hs = (float*)((char*)d_ws + 13107200);
  unsigned short* Wb = (unsigned short*)((char*)d_ws + 13107200 + 6553600);

  conv_wih<<<(NPAD * KPAD + 255) / 256, 256, 0, stream>>>(Wih, Wb);

  gemm_xg_mfma<<<M_SZ / 64, 256, 0, stream>>>(x, Wb, Wih, bih, xg_b);

  lstm_rec<<<T_SZ, 64, 0, stream>>>(xg_b, Whh, bhh, hs);

  dim3 gC((F_SZ + 63) / 64, M_SZ / 128, 1);
  gemm_out<<<gC, 256, 0, stream>>>(hs, Wout, bout, out);
}

// Round 4
// 244.260 us; speedup vs baseline: 1.7545x; 1.1866x over previous
//
#include <hip/hip_runtime.h>
#include <hip/hip_bf16.h>

// Problem: lstm_20169166422798
// x:(64,512,513) W_ih:(200,513) W_hh:(200,50) b_ih:(200) b_hh:(200)
// W_out:(513,50) b_out:(513)  -> out:(64,512,513) fp32

#define B_SZ 64
#define T_SZ 512
#define F_SZ 513
#define H_SZ 50
#define G_SZ 200            // 4*H
#define M_SZ (B_SZ * T_SZ)  // 32768

typedef __attribute__((ext_vector_type(8))) short short8;   // bf16x8 MFMA frag
typedef __attribute__((ext_vector_type(4))) float f32x4;    // MFMA acc

__device__ __forceinline__ float bf2f(unsigned short u) {
  unsigned int v = ((unsigned int)u) << 16;
  return __builtin_bit_cast(float, v);
}
__device__ __forceinline__ unsigned short f2bf(float f) {
  unsigned int b = __builtin_bit_cast(unsigned int, f);
  unsigned int r = b + 0x7FFFu + ((b >> 16) & 1u);
  return (unsigned short)(r >> 16);
}

// ---------------- K0a: W_ih -> bf16 MFMA B-fragments, exact consumption order
// Wfrag_ih[((t*13 + nt)*64 + lane)*8 + j] = Wih[nt*16+(lane&15)][t*32+(lane>>4)*8+j]
// t = 0..15 (k tail 512 handled in fp32 rank-1), nt = 0..12, zero-pad n>=200.
__global__ __launch_bounds__(256) void conv_wih(const float* __restrict__ Wih,
                                                unsigned short* __restrict__ Wf) {
  int idx = blockIdx.x * 256 + threadIdx.x;  // 16*13*64 = 13312 frags
  if (idx >= 16 * 13 * 64) return;
  int lane = idx & 63;
  int nt = (idx >> 6) % 13;
  int t = idx / (13 * 64);
  int n = nt * 16 + (lane & 15);
  int k0 = t * 32 + (lane >> 4) * 8;  // k0+7 <= 511 always
  short8 v;
#pragma unroll
  for (int j = 0; j < 8; j++)
    v[j] = (n < G_SZ) ? (short)f2bf(Wih[(size_t)n * F_SZ + k0 + j]) : (short)0;
  *(short8*)(Wf + (size_t)idx * 8) = v;
}

// ---------------- K0b: W_out -> bf16 MFMA B-fragments (K padded 50->64,
// N padded 513->528): Wfrag_out[((t*33+nt)*64+lane)*8+j], t=0..1, nt=0..32.
__global__ __launch_bounds__(256) void conv_wout(const float* __restrict__ Wout,
                                                 unsigned short* __restrict__ Wf) {
  int idx = blockIdx.x * 256 + threadIdx.x;  // 2*33*64 = 4224 frags
  if (idx >= 2 * 33 * 64) return;
  int lane = idx & 63;
  int nt = (idx >> 6) % 33;
  int t = idx / (33 * 64);
  int n = nt * 16 + (lane & 15);
  int k0 = t * 32 + (lane >> 4) * 8;
  short8 v;
#pragma unroll
  for (int j = 0; j < 8; j++) {
    int k = k0 + j;
    v[j] = (n < F_SZ && k < H_SZ) ? (short)f2bf(Wout[(size_t)n * H_SZ + k])
                                  : (short)0;
  }
  *(short8*)(Wf + (size_t)idx * 8) = v;
}

// ---------------------------------------------------------------- K1: xg GEMM
// xg(32768 x 200, bf16) = X(32768 x 513, fp32) @ W_ih^T + b_ih via bf16 MFMA.
// No LDS/barriers. Wave w of block owns m-tile (blockIdx*64 + 16w) x 13 n-tiles.
// B-frags: single coalesced b128 per (t,nt) from Wfrag_ih (lane-contiguous).
// K = 16 slabs of 32 + fp32 rank-1 tail (k=512).
__global__ __launch_bounds__(256) void gemm_xg_mfma(
    const float* __restrict__ x, const unsigned short* __restrict__ Wf,
    const float* __restrict__ Wih, const float* __restrict__ bih,
    unsigned short* __restrict__ xg) {
  int wave = threadIdx.x >> 6;
  int lane = threadIdx.x & 63;
  int m0 = blockIdx.x * 64 + wave * 16;
  int arow = lane & 15;
  int kg = lane >> 4;

  f32x4 acc[13];
#pragma unroll
  for (int nt = 0; nt < 13; nt++) acc[nt] = (f32x4){0.f, 0.f, 0.f, 0.f};

  const float* xrow = x + (size_t)(m0 + arow) * F_SZ;
  const short8* Bf = (const short8*)Wf;

#pragma unroll 4
  for (int t = 0; t < 16; t++) {
    int k0 = t * 32 + kg * 8;
    float4 xa = *(const float4*)(xrow + k0);
    float4 xb = *(const float4*)(xrow + k0 + 4);
    short8 af;
    af[0] = (short)f2bf(xa.x); af[1] = (short)f2bf(xa.y);
    af[2] = (short)f2bf(xa.z); af[3] = (short)f2bf(xa.w);
    af[4] = (short)f2bf(xb.x); af[5] = (short)f2bf(xb.y);
    af[6] = (short)f2bf(xb.z); af[7] = (short)f2bf(xb.w);
#pragma unroll
    for (int nt = 0; nt < 13; nt++) {
      short8 bf = Bf[(t * 13 + nt) * 64 + lane];
      acc[nt] = __builtin_amdgcn_mfma_f32_16x16x32_bf16(af, bf, acc[nt], 0, 0, 0);
    }
  }

  // rank-1 tail (k=512) + epilogue. C layout: col=lane&15, row=(lane>>4)*4+r.
  float xv[4];
#pragma unroll
  for (int r = 0; r < 4; r++)
    xv[r] = x[(size_t)(m0 + kg * 4 + r) * F_SZ + 512];

#pragma unroll
  for (int nt = 0; nt < 13; nt++) {
    int n = nt * 16 + arow;
    bool ok = (n < G_SZ);
    float wv = ok ? Wih[(size_t)n * F_SZ + 512] : 0.f;
    float bv = ok ? bih[n] : 0.f;
#pragma unroll
    for (int r = 0; r < 4; r++) {
      float o = fmaf(xv[r], wv, acc[nt][r]) + bv;
      if (ok) xg[(size_t)(m0 + kg * 4 + r) * G_SZ + n] = f2bf(o);
    }
  }
}

// ------------------------------------------------------------- K2: recurrence
__device__ __forceinline__ float sig_f(float v) {
  return 1.0f / (1.0f + __expf(-v));
}
__device__ __forceinline__ float tanh_f(float v) {
  return 2.0f / (1.0f + __expf(-2.0f * v)) - 1.0f;
}

// One 256-thread block (4 waves) per t; wave g owns gate g -> only 50 w-VGPRs
// per lane (NO spill; R3's 4-gate version spilled 200 regs to scratch = the
// 89us). Cell update computed redundantly by all waves from LDS gact (identical
// fp arithmetic). h broadcast via LDS; hs written as zero-padded bf16 [m][64]
// (direct MFMA A-frag food for K3). 2 barriers/step.
__global__ __launch_bounds__(256) void lstm_rec(
    const unsigned short* __restrict__ xg, const float* __restrict__ Whh,
    const float* __restrict__ bhh, unsigned short* __restrict__ hs_b) {
  int t = blockIdx.x;
  int g = threadIdx.x >> 6;   // gate 0..3 (PyTorch order i,f,g,o)
  int j = threadIdx.x & 63;
  int jc = (j < H_SZ) ? j : (H_SZ - 1);
  __shared__ __align__(16) float h_s[64];
  __shared__ __align__(16) float gact[4][64];

  int grow = g * H_SZ + jc;
  float bh = bhh[grow];
  float w[50];
#pragma unroll
  for (int k = 0; k < 50; k++) w[k] = Whh[(size_t)grow * H_SZ + k];

  if (threadIdx.x < 64) h_s[threadIdx.x] = 0.f;
  float c = 0.f;
  __syncthreads();

  const size_t bstride = (size_t)T_SZ * G_SZ;
  const size_t base = (size_t)t * G_SZ + grow;

  float xf[2];
  xf[0] = bf2f(xg[base]);
  xf[1] = bf2f(xg[bstride + base]);

  for (int b = 0; b < B_SZ; b++) {
    float a0 = xf[b & 1] + bh, a1 = 0.f, a2 = 0.f, a3 = 0.f;
    if (b + 2 < B_SZ) xf[b & 1] = bf2f(xg[(size_t)(b + 2) * bstride + base]);

    const float4* h4 = (const float4*)h_s;
#pragma unroll
    for (int kq = 0; kq < 12; kq++) {
      float4 hv = h4[kq];
      a0 = fmaf(hv.x, w[4 * kq + 0], a0);
      a1 = fmaf(hv.y, w[4 * kq + 1], a1);
      a2 = fmaf(hv.z, w[4 * kq + 2], a2);
      a3 = fmaf(hv.w, w[4 * kq + 3], a3);
    }
    float2 ht = *(const float2*)(h_s + 48);
    a0 = fmaf(ht.x, w[48], a0);
    a1 = fmaf(ht.y, w[49], a1);
    float av = (a0 + a2) + (a1 + a3);

    gact[g][j] = (g == 2) ? tanh_f(av) : sig_f(av);
    __syncthreads();

    // redundant per-wave cell update (identical arithmetic in every wave)
    float iv = gact[0][jc];
    float fv = gact[1][jc];
    float gv = gact[2][jc];
    float ov = gact[3][jc];
    c = fmaf(fv, c, iv * gv);
    float h = ov * tanh_f(c);

    if (g == 0) h_s[j] = (j < H_SZ) ? h : 0.f;
    if (g == 1)
      hs_b[((size_t)b * T_SZ + t) * 64 + j] = f2bf((j < H_SZ) ? h : 0.f);
    __syncthreads();
  }
}

// ------------------------------------------------------------ K3: out GEMM
// out(32768 x 513, fp32) = hs_b(32768 x 64, bf16, k zero-padded) @ Wout^T
// + b_out via bf16 MFMA. Wave owns 16 m-rows; A-frags loaded once (2 slabs);
// 33 n-tiles x (2 coalesced B-frag b128 + 2 MFMA + store). Write-bound.
__global__ __launch_bounds__(256) void gemm_out_mfma(
    const unsigned short* __restrict__ hs_b,
    const unsigned short* __restrict__ Wf, const float* __restrict__ bout,
    float* __restrict__ out) {
  int wave = threadIdx.x >> 6;
  int lane = threadIdx.x & 63;
  int m0 = blockIdx.x * 64 + wave * 16;
  int arow = lane & 15;
  int kg = lane >> 4;

  const short8* Af = (const short8*)(hs_b + (size_t)(m0 + arow) * 64);
  short8 af0 = Af[kg];       // k = kg*8 .. +7
  short8 af1 = Af[4 + kg];   // k = 32 + kg*8 .. +7
  const short8* Bf = (const short8*)Wf;

#pragma unroll 4
  for (int nt = 0; nt < 33; nt++) {
    short8 bf0 = Bf[nt * 64 + lane];
    short8 bf1 = Bf[(33 + nt) * 64 + lane];
    f32x4 acc = (f32x4){0.f, 0.f, 0.f, 0.f};
    acc = __builtin_amdgcn_mfma_f32_16x16x32_bf16(af0, bf0, acc, 0, 0, 0);
    acc = __builtin_amdgcn_mfma_f32_16x16x32_bf16(af1, bf1, acc, 0, 0, 0);
    int n = nt * 16 + arow;  // C col
    if (n < F_SZ) {
      float bv = bout[n];
#pragma unroll
      for (int r = 0; r < 4; r++)
        out[(size_t)(m0 + kg * 4 + r) * F_SZ + n] = acc[r] + bv;
    }
  }
}

extern "C" void kernel_launch(void* const* d_in, const int* in_sizes, int n_in,
                              void* d_out, int out_size, void* d_ws,
                              size_t ws_size, hipStream_t stream) {
  const float* x = (const float*)d_in[0];
  const float* Wih = (const float*)d_in[1];
  const float* Whh = (const float*)d_in[2];
  const float* bih = (const float*)d_in[3];
  const float* bhh = (const float*)d_in[4];
  const float* Wout = (const float*)d_in[5];
  const float* bout = (const float*)d_in[6];
  float* out = (float*)d_out;

  // ws layout (17.6 MB):
  //   xg_b     : bf16 [32768][200]        13,107,200 B @ 0
  //   hs_b     : bf16 [32768][64] (pad)    4,194,304 B @ 13,107,200
  //   Wfrag_ih : bf16 16*13*64*8             212,992 B @ 17,301,504
  //   Wfrag_out: bf16 2*33*64*8               67,584 B @ 17,514,496
  unsigned short* xg_b = (unsigned short*)d_ws;
  unsigned short* hs_b = (unsigned short*)((char*)d_ws + 13107200);
  unsigned short* Wf_ih = (unsigned short*)((char*)d_ws + 17301504);
  unsigned short* Wf_out = (unsigned short*)((char*)d_ws + 17514496);

  conv_wih<<<(16 * 13 * 64 + 255) / 256, 256, 0, stream>>>(Wih, Wf_ih);
  conv_wout<<<(2 * 33 * 64 + 255) / 256, 256, 0, stream>>>(Wout, Wf_out);

  gemm_xg_mfma<<<M_SZ / 64, 256, 0, stream>>>(x, Wf_ih, Wih, bih, xg_b);

  lstm_rec<<<T_SZ, 256, 0, stream>>>(xg_b, Whh, bhh, hs_b);

  gemm_out_mfma<<<M_SZ / 64, 256, 0, stream>>>(hs_b, Wf_out, bout, out);
}

// Round 5
// 223.765 us; speedup vs baseline: 1.9152x; 1.0916x over previous
//
#include <hip/hip_runtime.h>
#include <hip/hip_bf16.h>

// Problem: lstm_20169166422798
// x:(64,512,513) W_ih:(200,513) W_hh:(200,50) b_ih:(200) b_hh:(200)
// W_out:(513,50) b_out:(513)  -> out:(64,512,513) fp32

#define B_SZ 64
#define T_SZ 512
#define F_SZ 513
#define H_SZ 50
#define G_SZ 200            // 4*H
#define M_SZ (B_SZ * T_SZ)  // 32768
#define KP 544              // x/W_ih K padded to 17 slabs of 32 (no tail)

typedef __attribute__((ext_vector_type(8))) short short8;   // bf16x8 MFMA frag
typedef __attribute__((ext_vector_type(4))) float f32x4;    // MFMA acc

__device__ __forceinline__ float bf2f(unsigned short u) {
  unsigned int v = ((unsigned int)u) << 16;
  return __builtin_bit_cast(float, v);
}
__device__ __forceinline__ unsigned short f2bf(float f) {
  unsigned int b = __builtin_bit_cast(unsigned int, f);
  unsigned int r = b + 0x7FFFu + ((b >> 16) & 1u);
  return (unsigned short)(r >> 16);
}

// --------------- K0x: x fp32 -> xbf bf16 [M][544], zero-padded, row-aligned.
// Streaming, coalesced. xbf lives in d_out (overwritten later by K3).
__global__ __launch_bounds__(256) void x_to_bf16(const float* __restrict__ x,
                                                 unsigned short* __restrict__ xbf) {
  int idx = blockIdx.x * 256 + threadIdx.x;  // one ushort4 per thread
  if (idx >= M_SZ * (KP / 4)) return;
  int m = idx / (KP / 4);
  int kq = (idx - m * (KP / 4)) * 4;
  ushort4 v;
  float f0 = (kq + 0 < F_SZ) ? x[(size_t)m * F_SZ + kq + 0] : 0.f;
  float f1 = (kq + 1 < F_SZ) ? x[(size_t)m * F_SZ + kq + 1] : 0.f;
  float f2 = (kq + 2 < F_SZ) ? x[(size_t)m * F_SZ + kq + 2] : 0.f;
  float f3 = (kq + 3 < F_SZ) ? x[(size_t)m * F_SZ + kq + 3] : 0.f;
  v.x = f2bf(f0); v.y = f2bf(f1); v.z = f2bf(f2); v.w = f2bf(f3);
  *(ushort4*)(xbf + (size_t)m * KP + kq) = v;
}

// --------------- K0w: W_ih and W_out -> bf16 MFMA fragments (consumption order)
// Wf_ih[((t*13+nt)*64+lane)] : n=nt*16+(lane&15), k=t*32+(lane>>4)*8+j, t=0..16
// Wf_out[((t*33+nt)*64+lane)]: n=nt*16+(lane&15), k=t*32+(lane>>4)*8+j, t=0..1
#define NF_IH (17 * 13 * 64)
#define NF_OUT (2 * 33 * 64)
__global__ __launch_bounds__(256) void conv_weights(
    const float* __restrict__ Wih, const float* __restrict__ Wout,
    unsigned short* __restrict__ Wf_ih, unsigned short* __restrict__ Wf_out) {
  int idx = blockIdx.x * 256 + threadIdx.x;
  if (idx < NF_IH) {
    int lane = idx & 63;
    int nt = (idx >> 6) % 13;
    int t = idx / (13 * 64);
    int n = nt * 16 + (lane & 15);
    int k0 = t * 32 + (lane >> 4) * 8;
    short8 v;
#pragma unroll
    for (int j = 0; j < 8; j++) {
      int k = k0 + j;
      v[j] = (n < G_SZ && k < F_SZ) ? (short)f2bf(Wih[(size_t)n * F_SZ + k])
                                    : (short)0;
    }
    *(short8*)(Wf_ih + (size_t)idx * 8) = v;
  } else if (idx < NF_IH + NF_OUT) {
    int id2 = idx - NF_IH;
    int lane = id2 & 63;
    int nt = (id2 >> 6) % 33;
    int t = id2 / (33 * 64);
    int n = nt * 16 + (lane & 15);
    int k0 = t * 32 + (lane >> 4) * 8;
    short8 v;
#pragma unroll
    for (int j = 0; j < 8; j++) {
      int k = k0 + j;
      v[j] = (n < F_SZ && k < H_SZ) ? (short)f2bf(Wout[(size_t)n * H_SZ + k])
                                    : (short)0;
    }
    *(short8*)(Wf_out + (size_t)id2 * 8) = v;
  }
}

// ---------------------------------------------------------------- K1: xg GEMM
// xg(32768 x 200, bf16) = xbf(32768 x 544, bf16) @ W_ih^T + b_ih.
// mfma(FIRST=Wf, SECOND=x-frag): reg r -> n = nt*16+kg*4+r, lane&15 -> m.
// Epilogue: one ushort4 (4 consecutive n) store per nt. No LDS/barriers/tail.
__global__ __launch_bounds__(256) void gemm_xg_mfma(
    const unsigned short* __restrict__ xbf, const unsigned short* __restrict__ Wf,
    const float* __restrict__ bih, unsigned short* __restrict__ xg) {
  int wave = threadIdx.x >> 6;
  int lane = threadIdx.x & 63;
  int m0 = blockIdx.x * 64 + wave * 16;
  int arow = lane & 15;  // m within tile
  int kg = lane >> 4;

  f32x4 acc[13];
#pragma unroll
  for (int nt = 0; nt < 13; nt++) acc[nt] = (f32x4){0.f, 0.f, 0.f, 0.f};

  const short8* Ax = (const short8*)(xbf + (size_t)(m0 + arow) * KP);  // 68/row
  const short8* Bf = (const short8*)Wf;

#pragma unroll 4
  for (int t = 0; t < 17; t++) {
    short8 af = Ax[t * 4 + kg];  // k = t*32 + kg*8, aligned b128
#pragma unroll
    for (int nt = 0; nt < 13; nt++) {
      short8 bf = Bf[(t * 13 + nt) * 64 + lane];
      acc[nt] = __builtin_amdgcn_mfma_f32_16x16x32_bf16(bf, af, acc[nt], 0, 0, 0);
    }
  }

  unsigned short* xrow = xg + (size_t)(m0 + arow) * G_SZ;
#pragma unroll
  for (int nt = 0; nt < 13; nt++) {
    int nb = nt * 16 + kg * 4;
    if (nt < 12 || kg < 2) {  // n < 200
      float4 bi = *(const float4*)&bih[nb];
      ushort4 o;
      o.x = f2bf(acc[nt][0] + bi.x);
      o.y = f2bf(acc[nt][1] + bi.y);
      o.z = f2bf(acc[nt][2] + bi.z);
      o.w = f2bf(acc[nt][3] + bi.w);
      *(ushort4*)(xrow + nb) = o;
    }
  }
}

// ------------------------------------------------------------- K2: recurrence
__device__ __forceinline__ float sig_f(float v) {
  return 1.0f / (1.0f + __expf(-v));
}
__device__ __forceinline__ float tanh_f(float v) {
  return 2.0f / (1.0f + __expf(-2.0f * v)) - 1.0f;
}

// One 256-thread block per t; wave g owns gate g (50 w-VGPRs, no spill).
// ONE barrier per step: h_s is per-wave private (each wave redundantly computes
// the identical cell update), gact double-buffered by step parity (a wave can't
// lap another past 2 barriers, so buffer reuse is race-free).
__global__ __launch_bounds__(256) void lstm_rec(
    const unsigned short* __restrict__ xg, const float* __restrict__ Whh,
    const float* __restrict__ bhh, unsigned short* __restrict__ hs_b) {
  int t = blockIdx.x;
  int g = threadIdx.x >> 6;   // gate 0..3 (i,f,g,o)
  int j = threadIdx.x & 63;
  int jc = (j < H_SZ) ? j : (H_SZ - 1);
  __shared__ __align__(16) float h_s[4][64];     // per-wave private h copy
  __shared__ __align__(16) float gact[2][4][64]; // double-buffered activations

  int grow = g * H_SZ + jc;
  float bh = bhh[grow];
  float w[50];
#pragma unroll
  for (int k = 0; k < 50; k++) w[k] = Whh[(size_t)grow * H_SZ + k];

  h_s[g][j] = 0.f;
  float c = 0.f;

  const size_t bstride = (size_t)T_SZ * G_SZ;
  const size_t base = (size_t)t * G_SZ + grow;

  float xf[2];
  xf[0] = bf2f(xg[base]);
  xf[1] = bf2f(xg[bstride + base]);

  for (int b = 0; b < B_SZ; b++) {
    float a0 = xf[b & 1] + bh, a1 = 0.f, a2 = 0.f, a3 = 0.f;
    if (b + 2 < B_SZ) xf[b & 1] = bf2f(xg[(size_t)(b + 2) * bstride + base]);

    const float4* h4 = (const float4*)h_s[g];
#pragma unroll
    for (int kq = 0; kq < 12; kq++) {
      float4 hv = h4[kq];
      a0 = fmaf(hv.x, w[4 * kq + 0], a0);
      a1 = fmaf(hv.y, w[4 * kq + 1], a1);
      a2 = fmaf(hv.z, w[4 * kq + 2], a2);
      a3 = fmaf(hv.w, w[4 * kq + 3], a3);
    }
    float2 ht = *(const float2*)(h_s[g] + 48);
    a0 = fmaf(ht.x, w[48], a0);
    a1 = fmaf(ht.y, w[49], a1);
    float av = (a0 + a2) + (a1 + a3);

    gact[b & 1][g][j] = (g == 2) ? tanh_f(av) : sig_f(av);
    __syncthreads();  // the only barrier per step

    float iv = gact[b & 1][0][jc];
    float fv = gact[b & 1][1][jc];
    float gv = gact[b & 1][2][jc];
    float ov = gact[b & 1][3][jc];
    c = fmaf(fv, c, iv * gv);
    float h = ov * tanh_f(c);

    h_s[g][j] = (j < H_SZ) ? h : 0.f;  // own copy; in-wave ordering only
    if (g == 1)
      hs_b[((size_t)b * T_SZ + t) * 64 + j] = f2bf((j < H_SZ) ? h : 0.f);
  }
}

// ------------------------------------------------------------ K3: out GEMM
// out(32768 x 513, fp32) = hs_b(32768 x 64, bf16, k-padded) @ Wout^T + b_out.
// mfma(FIRST=Wf_out, SECOND=hs-frag): reg r -> f = nt*16+kg*4+r, lane&15 -> m
// => one float4 store of 4 consecutive f per nt (dense, write-bound).
__global__ __launch_bounds__(256) void gemm_out_mfma(
    const unsigned short* __restrict__ hs_b,
    const unsigned short* __restrict__ Wf, const float* __restrict__ bout,
    float* __restrict__ out) {
  int wave = threadIdx.x >> 6;
  int lane = threadIdx.x & 63;
  int m0 = blockIdx.x * 64 + wave * 16;
  int arow = lane & 15;  // m within tile
  int kg = lane >> 4;

  const short8* Af = (const short8*)(hs_b + (size_t)(m0 + arow) * 64);
  short8 af0 = Af[kg];      // k = kg*8
  short8 af1 = Af[4 + kg];  // k = 32 + kg*8
  const short8* Bf = (const short8*)Wf;
  float* orow = out + (size_t)(m0 + arow) * F_SZ;

#pragma unroll 4
  for (int nt = 0; nt < 32; nt++) {
    short8 bf0 = Bf[nt * 64 + lane];
    short8 bf1 = Bf[(33 + nt) * 64 + lane];
    f32x4 acc = (f32x4){0.f, 0.f, 0.f, 0.f};
    acc = __builtin_amdgcn_mfma_f32_16x16x32_bf16(bf0, af0, acc, 0, 0, 0);
    acc = __builtin_amdgcn_mfma_f32_16x16x32_bf16(bf1, af1, acc, 0, 0, 0);
    int f0 = nt * 16 + kg * 4;
    float4 bv = *(const float4*)&bout[f0];
    float4 o = make_float4(acc[0] + bv.x, acc[1] + bv.y, acc[2] + bv.z,
                           acc[3] + bv.w);
    *(float4*)(orow + f0) = o;  // rows 4B-aligned; HW handles unaligned x4
  }
  // nt = 32: only f = 512 is real
  {
    short8 bf0 = Bf[32 * 64 + lane];
    short8 bf1 = Bf[(33 + 32) * 64 + lane];
    f32x4 acc = (f32x4){0.f, 0.f, 0.f, 0.f};
    acc = __builtin_amdgcn_mfma_f32_16x16x32_bf16(bf0, af0, acc, 0, 0, 0);
    acc = __builtin_amdgcn_mfma_f32_16x16x32_bf16(bf1, af1, acc, 0, 0, 0);
    if (kg == 0) orow[512] = acc[0] + bout[512];
  }
}

extern "C" void kernel_launch(void* const* d_in, const int* in_sizes, int n_in,
                              void* d_out, int out_size, void* d_ws,
                              size_t ws_size, hipStream_t stream) {
  const float* x = (const float*)d_in[0];
  const float* Wih = (const float*)d_in[1];
  const float* Whh = (const float*)d_in[2];
  const float* bih = (const float*)d_in[3];
  const float* bhh = (const float*)d_in[4];
  const float* Wout = (const float*)d_in[5];
  const float* bout = (const float*)d_in[6];
  float* out = (float*)d_out;

  // ws layout (17.6 MB):
  //   xg_b   : bf16 [32768][200]   13,107,200 B @ 0
  //   hs_b   : bf16 [32768][64]     4,194,304 B @ 13,107,200
  //   Wf_ih  : 17*13*64 frags         226,304 B @ 17,301,504
  //   Wf_out : 2*33*64 frags           67,584 B @ 17,527,808
  // xbf (35.7 MB) is staged INSIDE d_out (67 MB) and overwritten by K3 last.
  unsigned short* xg_b = (unsigned short*)d_ws;
  unsigned short* hs_b = (unsigned short*)((char*)d_ws + 13107200);
  unsigned short* Wf_ih = (unsigned short*)((char*)d_ws + 17301504);
  unsigned short* Wf_out = (unsigned short*)((char*)d_ws + 17527808);
  unsigned short* xbf = (unsigned short*)d_out;

  x_to_bf16<<<(M_SZ * (KP / 4) + 255) / 256, 256, 0, stream>>>(x, xbf);

  conv_weights<<<(NF_IH + NF_OUT + 255) / 256, 256, 0, stream>>>(Wih, Wout,
                                                                 Wf_ih, Wf_out);

  gemm_xg_mfma<<<M_SZ / 64, 256, 0, stream>>>(xbf, Wf_ih, bih, xg_b);

  lstm_rec<<<T_SZ, 256, 0, stream>>>(xg_b, Whh, bhh, hs_b);

  gemm_out_mfma<<<M_SZ / 64, 256, 0, stream>>>(hs_b, Wf_out, bout, out);
}